// Round 1
// baseline (1243.767 us; speedup 1.0000x reference)
//
#include <hip/hip_runtime.h>
#include <hip/hip_bf16.h>

// ---------------------------------------------------------------------------
// WeightOnlyLinear: y = x @ dequant4(qweight, scales, qzeros) + bias
//   x:       (M=8192, K=4096) fp32
//   scales:  (G=32, N=12288) fp32         (GROUPSIZE=128 along K)
//   bias:    (N,) fp32
//   qweight: (K/8, N) int32, 4-bit packed along K (element k -> word k/8, bits 4*(k%8))
//   qzeros:  (G, N/8) int32, 4-bit packed along N; zp = nibble + 1
//   out:     (M, N) fp32
//
// Strategy: dequant W -> bf16 transposed (N x K) in ws, convert x -> bf16 in
// ws, then m97-style 128x128x64 bf16 MFMA GEMM with global_load_lds staging
// and fused bias epilogue.
// ---------------------------------------------------------------------------

typedef __attribute__((ext_vector_type(8))) short short8;
typedef __attribute__((ext_vector_type(4))) float f32x4;

__device__ __forceinline__ short f2bf(float f) {
  // round-to-nearest-even fp32 -> bf16 (no NaN handling needed here)
  unsigned u = __float_as_uint(f);
  u += 0x7fffu + ((u >> 16) & 1u);
  return (short)(u >> 16);
}

__device__ __forceinline__ void gload_lds16(const void* g, void* l) {
  __builtin_amdgcn_global_load_lds(
      (const __attribute__((address_space(1))) void*)g,
      (__attribute__((address_space(3))) void*)l,
      16, 0, 0);
}

// ---------------------------------------------------------------------------
// Pass 1: dequant + transpose.  qweight (K/8, N) int32 -> Wt (N, K) bf16.
// Tile: 64 n-cols x 64 k (8 packed words). One thread: 2 words -> 16 bf16.
// LDS transpose so global reads (along n) AND writes (along k) coalesce.
// grid = (N/64, K/64), block = 256.
// ---------------------------------------------------------------------------
__global__ __launch_bounds__(256) void dequant_kernel(
    const int* __restrict__ qweight, const int* __restrict__ qzeros,
    const float* __restrict__ scales, short* __restrict__ Wt,
    int in_f, int out_f) {
  __shared__ __align__(16) short T[64][72];  // [n_local][k_local], +8 pad
  const int n0 = blockIdx.x * 64;
  const int k0 = blockIdx.y * 64;
  const int t = threadIdx.x;
  const int nl = t & 63;   // n within tile
  const int kw = t >> 6;   // word row 0..3 (and +4)
  const int n = n0 + nl;
  const int g = k0 >> 7;   // group (GROUPSIZE=128); 64-k tile is within one group
  const float sc = scales[(size_t)g * out_f + n];
  const int zpw = qzeros[(size_t)g * (out_f >> 3) + (n >> 3)];
  const float zp = (float)(((zpw >> ((n & 7) * 4)) & 15) + 1);
  const float zs = zp * sc;
#pragma unroll
  for (int rr = 0; rr < 2; ++rr) {
    const int kwi = kw + rr * 4;  // 0..7
    const int w = qweight[(size_t)((k0 >> 3) + kwi) * out_f + n];
    short8 v;
#pragma unroll
    for (int e = 0; e < 8; ++e) {
      float f = (float)((w >> (4 * e)) & 15) * sc - zs;
      v[e] = f2bf(f);
    }
    *(short8*)&T[nl][kwi * 8] = v;
  }
  __syncthreads();
  // write out: 512 chunks of 16B; chunk c -> row c/8 (n), chunk c%8 (k)
#pragma unroll
  for (int rr = 0; rr < 2; ++rr) {
    const int c = rr * 256 + t;
    const int row = c >> 3, ch = c & 7;
    *(short8*)&Wt[(size_t)(n0 + row) * in_f + k0 + ch * 8] =
        *(const short8*)&T[row][ch * 8];
  }
}

// ---------------------------------------------------------------------------
// Pass 2: x fp32 -> bf16. 8 elements / thread.
// ---------------------------------------------------------------------------
__global__ __launch_bounds__(256) void cvt_kernel(
    const float* __restrict__ x, short* __restrict__ xb, long n8) {
  long i = (long)blockIdx.x * blockDim.x + threadIdx.x;
  if (i >= n8) return;
  const float* src = x + i * 8;
  float4 a = *(const float4*)src;
  float4 b = *(const float4*)(src + 4);
  short8 v;
  v[0] = f2bf(a.x); v[1] = f2bf(a.y); v[2] = f2bf(a.z); v[3] = f2bf(a.w);
  v[4] = f2bf(b.x); v[5] = f2bf(b.y); v[6] = f2bf(b.z); v[7] = f2bf(b.w);
  *(short8*)(xb + i * 8) = v;
}

// ---------------------------------------------------------------------------
// Pass 3: GEMM.  A (M,K) bf16 [or fp32 converted in-staging], Bt (N,K) bf16,
// C (M,N) fp32 = A*Bt^T + bias.
// BM=BN=128, BK=64, 256 threads = 4 waves in 2x2, each wave 64x64 out
// = 4x4 frags of 16x16, mfma_f32_16x16x32_bf16.
// ---------------------------------------------------------------------------
#define BM 128
#define BN 128
#define BK 64

template <bool A_BF16>
__global__ __launch_bounds__(256) void gemm_bias_kernel(
    const void* __restrict__ Av, const short* __restrict__ Bt,
    const float* __restrict__ bias, float* __restrict__ C,
    int M, int N, int K) {
  __shared__ __align__(16) short As[BM * BK];  // [128][64] row-major (m, k)
  __shared__ __align__(16) short Bs[BN * BK];  // [128][64] row-major (n, k)
  const int tid = threadIdx.x;
  const int bm = blockIdx.y * BM;
  const int bn = blockIdx.x * BN;
  const int wid = tid >> 6, lane = tid & 63;
  const int wr = wid >> 1, wc = wid & 1;  // wave 2x2 grid
  const int lrow = lane & 15;             // row/col within 16x16 frag
  const int lk = (lane >> 4) * 8;         // k-offset of this lane's 8 elements

  f32x4 acc[4][4] = {};

  for (int kt = 0; kt < K; kt += BK) {
    // ---- stage A and B tiles (16 KB each) ----
    if constexpr (A_BF16) {
      const short* A = (const short*)Av;
#pragma unroll
      for (int r = 0; r < 4; ++r) {
        const int c = r * 256 + tid;
        const int row = c >> 3, ch = c & 7;
        gload_lds16(A + (size_t)(bm + row) * K + kt + ch * 8,
                    (char*)As + c * 16);
      }
    } else {
      const float* A = (const float*)Av;
#pragma unroll
      for (int r = 0; r < 4; ++r) {
        const int c = r * 256 + tid;
        const int row = c >> 3, ch = c & 7;
        const float* src = A + (size_t)(bm + row) * K + kt + ch * 8;
        float4 f0 = *(const float4*)src;
        float4 f1 = *(const float4*)(src + 4);
        short8 v;
        v[0] = f2bf(f0.x); v[1] = f2bf(f0.y); v[2] = f2bf(f0.z); v[3] = f2bf(f0.w);
        v[4] = f2bf(f1.x); v[5] = f2bf(f1.y); v[6] = f2bf(f1.z); v[7] = f2bf(f1.w);
        *(short8*)((char*)As + c * 16) = v;
      }
    }
#pragma unroll
    for (int r = 0; r < 4; ++r) {
      const int c = r * 256 + tid;
      const int row = c >> 3, ch = c & 7;
      gload_lds16(Bt + (size_t)(bn + row) * K + kt + ch * 8,
                  (char*)Bs + c * 16);
    }
    __syncthreads();  // drains vmcnt (global_load_lds) + lgkmcnt

    // ---- compute: 2 k-steps of 32, 4x4 frags ----
#pragma unroll
    for (int kk = 0; kk < 2; ++kk) {
      short8 af[4], bf[4];
#pragma unroll
      for (int i = 0; i < 4; ++i)
        af[i] = *(const short8*)&As[(wr * 64 + i * 16 + lrow) * BK + kk * 32 + lk];
#pragma unroll
      for (int j = 0; j < 4; ++j)
        bf[j] = *(const short8*)&Bs[(wc * 64 + j * 16 + lrow) * BK + kk * 32 + lk];
#pragma unroll
      for (int i = 0; i < 4; ++i)
#pragma unroll
        for (int j = 0; j < 4; ++j)
          acc[i][j] = __builtin_amdgcn_mfma_f32_16x16x32_bf16(
              af[i], bf[j], acc[i][j], 0, 0, 0);
    }
    __syncthreads();
  }

  // ---- epilogue: C = acc + bias ----
  // C/D layout: col = lane&15, row = (lane>>4)*4 + reg
  const int crow0 = bm + wr * 64 + (lane >> 4) * 4;
  const int ccol0 = bn + wc * 64 + (lane & 15);
#pragma unroll
  for (int j = 0; j < 4; ++j) {
    const float bv = bias[ccol0 + j * 16];
#pragma unroll
    for (int i = 0; i < 4; ++i) {
#pragma unroll
      for (int r = 0; r < 4; ++r) {
        C[(size_t)(crow0 + i * 16 + r) * N + ccol0 + j * 16] = acc[i][j][r] + bv;
      }
    }
  }
}

// ---------------------------------------------------------------------------
// Last-resort fallback (ws too small): naive fused dequant GEMM. Correct, slow.
// ---------------------------------------------------------------------------
__global__ __launch_bounds__(256) void naive_kernel(
    const float* __restrict__ x, const float* __restrict__ scales,
    const float* __restrict__ bias, const int* __restrict__ qw,
    const int* __restrict__ qz, float* __restrict__ out,
    int M, int K, int N) {
  long idx = (long)blockIdx.x * blockDim.x + threadIdx.x;
  if (idx >= (long)M * N) return;
  const int n = (int)(idx % N);
  const int m = (int)(idx / N);
  float acc = 0.f;
  for (int g = 0; g < K / 128; ++g) {
    const float sc = scales[(size_t)g * N + n];
    const float zp =
        (float)(((qz[(size_t)g * (N >> 3) + (n >> 3)] >> ((n & 7) * 4)) & 15) + 1);
    const float zs = zp * sc;
    for (int kw = 0; kw < 16; ++kw) {
      const int w = qw[(size_t)(g * 16 + kw) * N + n];
      const float* xp = &x[(size_t)m * K + g * 128 + kw * 8];
#pragma unroll
      for (int e = 0; e < 8; ++e)
        acc += xp[e] * ((float)((w >> (4 * e)) & 15) * sc - zs);
    }
  }
  out[idx] = acc + bias[n];
}

// ---------------------------------------------------------------------------
extern "C" void kernel_launch(void* const* d_in, const int* in_sizes, int n_in,
                              void* d_out, int out_size, void* d_ws,
                              size_t ws_size, hipStream_t stream) {
  const float* x = (const float*)d_in[0];
  const float* scales = (const float*)d_in[1];
  const float* bias = (const float*)d_in[2];
  const int* qweight = (const int*)d_in[3];
  const int* qzeros = (const int*)d_in[4];
  float* out = (float*)d_out;

  const int out_f = in_sizes[2];               // 12288
  const int kwords = in_sizes[3] / out_f;      // 512
  const int in_f = kwords * 8;                 // 4096
  const int tokens = in_sizes[0] / in_f;       // 8192
  const int M = tokens, K = in_f, N = out_f;

  const size_t wt_bytes = (size_t)K * N * sizeof(short);      // 100.7 MB
  const size_t xb_bytes = (size_t)M * K * sizeof(short);      // 67 MB

  const bool divisible = (M % BM == 0) && (N % BN == 0) && (K % BK == 0) &&
                         (K % 128 == 0) && (N % 64 == 0);

  if (divisible && ws_size >= wt_bytes + xb_bytes) {
    short* Wt = (short*)d_ws;
    short* xb = (short*)((char*)d_ws + wt_bytes);
    dequant_kernel<<<dim3(N / 64, K / 64), 256, 0, stream>>>(
        qweight, qzeros, scales, Wt, K, N);
    const long n8 = (long)M * K / 8;
    cvt_kernel<<<(int)((n8 + 255) / 256), 256, 0, stream>>>(x, xb, n8);
    gemm_bias_kernel<true><<<dim3(N / BN, M / BM), 256, 0, stream>>>(
        xb, Wt, bias, out, M, N, K);
  } else if (divisible && ws_size >= wt_bytes) {
    short* Wt = (short*)d_ws;
    dequant_kernel<<<dim3(N / 64, K / 64), 256, 0, stream>>>(
        qweight, qzeros, scales, Wt, K, N);
    gemm_bias_kernel<false><<<dim3(N / BN, M / BM), 256, 0, stream>>>(
        x, Wt, bias, out, M, N, K);
  } else {
    const long total = (long)M * N;
    naive_kernel<<<(int)((total + 255) / 256), 256, 0, stream>>>(
        x, scales, bias, qweight, qzeros, out, M, K, N);
  }
}

// Round 2
// 926.007 us; speedup vs baseline: 1.3432x; 1.3432x over previous
//
#include <hip/hip_runtime.h>
#include <hip/hip_bf16.h>

// ---------------------------------------------------------------------------
// WeightOnlyLinear: y = x @ dequant4(qweight, scales, qzeros) + bias
//   x (8192,4096) fp32 | scales (32,12288) | bias (12288) | qweight (512,12288)
//   qzeros (32,1536) | out (8192,12288) fp32
// R2: 256x256x64 8-wave GEMM with T1 XCD swizzle + T2 LDS XOR swizzle +
//     T3/T4 counted-vmcnt 2-deep pipeline (raw s_barrier) + T5 setprio.
// ---------------------------------------------------------------------------

typedef __attribute__((ext_vector_type(8))) short short8;
typedef __attribute__((ext_vector_type(4))) float f32x4;

__device__ __forceinline__ short f2bf(float f) {
  unsigned u = __float_as_uint(f);
  u += 0x7fffu + ((u >> 16) & 1u);
  return (short)(u >> 16);
}

__device__ __forceinline__ void gload_lds16(const void* g, void* l) {
  __builtin_amdgcn_global_load_lds(
      (const __attribute__((address_space(1))) void*)g,
      (__attribute__((address_space(3))) void*)l,
      16, 0, 0);
}

__device__ __forceinline__ void bar() {
  asm volatile("" ::: "memory");
  __builtin_amdgcn_s_barrier();
  asm volatile("" ::: "memory");
}
__device__ __forceinline__ void wait_vm8() {
  asm volatile("s_waitcnt vmcnt(8)" ::: "memory");
}
__device__ __forceinline__ void wait_vm0() {
  asm volatile("s_waitcnt vmcnt(0)" ::: "memory");
}

// ---------------------------------------------------------------------------
// Pass 1: dequant + transpose. qweight (K/8, N) int32 -> Wt (N, K) bf16.
// ---------------------------------------------------------------------------
__global__ __launch_bounds__(256) void dequant_kernel(
    const int* __restrict__ qweight, const int* __restrict__ qzeros,
    const float* __restrict__ scales, short* __restrict__ Wt,
    int in_f, int out_f) {
  __shared__ __align__(16) short T[64][72];
  const int n0 = blockIdx.x * 64;
  const int k0 = blockIdx.y * 64;
  const int t = threadIdx.x;
  const int nl = t & 63;
  const int kw = t >> 6;
  const int n = n0 + nl;
  const int g = k0 >> 7;
  const float sc = scales[(size_t)g * out_f + n];
  const int zpw = qzeros[(size_t)g * (out_f >> 3) + (n >> 3)];
  const float zp = (float)(((zpw >> ((n & 7) * 4)) & 15) + 1);
  const float zs = zp * sc;
#pragma unroll
  for (int rr = 0; rr < 2; ++rr) {
    const int kwi = kw + rr * 4;
    const int w = qweight[(size_t)((k0 >> 3) + kwi) * out_f + n];
    short8 v;
#pragma unroll
    for (int e = 0; e < 8; ++e) {
      float f = (float)((w >> (4 * e)) & 15) * sc - zs;
      v[e] = f2bf(f);
    }
    *(short8*)&T[nl][kwi * 8] = v;
  }
  __syncthreads();
#pragma unroll
  for (int rr = 0; rr < 2; ++rr) {
    const int c = rr * 256 + t;
    const int row = c >> 3, ch = c & 7;
    *(short8*)&Wt[(size_t)(n0 + row) * in_f + k0 + ch * 8] =
        *(const short8*)&T[row][ch * 8];
  }
}

// ---------------------------------------------------------------------------
// Pass 2: x fp32 -> bf16.
// ---------------------------------------------------------------------------
__global__ __launch_bounds__(256) void cvt_kernel(
    const float* __restrict__ x, short* __restrict__ xb, long n8) {
  long i = (long)blockIdx.x * blockDim.x + threadIdx.x;
  if (i >= n8) return;
  const float* src = x + i * 8;
  float4 a = *(const float4*)src;
  float4 b = *(const float4*)(src + 4);
  short8 v;
  v[0] = f2bf(a.x); v[1] = f2bf(a.y); v[2] = f2bf(a.z); v[3] = f2bf(a.w);
  v[4] = f2bf(b.x); v[5] = f2bf(b.y); v[6] = f2bf(b.z); v[7] = f2bf(b.w);
  *(short8*)(xb + i * 8) = v;
}

// ---------------------------------------------------------------------------
// Pass 3 (R2): 256x256x64 GEMM, 512 threads = 8 waves (2M x 4N).
// Per wave: 128x64 output = 8x4 frags of 16x16, mfma_f32_16x16x32_bf16.
// LDS: 2 buffers x (A 256x64 + B 256x64) bf16 = 128 KiB, XOR chunk-swizzled.
// Pipeline: 2-deep counted vmcnt(8); stage tile t+2 into the buffer just
// finished reading; raw s_barrier (no vmcnt(0) drain in steady state).
// ---------------------------------------------------------------------------
#define GBM 256
#define GBN 256
#define GBK 64

__global__ __launch_bounds__(512, 2) void gemm256_kernel(
    const short* __restrict__ A, const short* __restrict__ Bt,
    const float* __restrict__ bias, float* __restrict__ C,
    int M, int N, int K) {
  __shared__ __align__(16) short lds[2][2][GBM * GBK];  // [buf][A/B][row*64+k]
  const int tid = threadIdx.x;
  const int nbx = N / GBN;
  const int nwg = gridDim.x;
  int bid = blockIdx.x;
  if ((nwg & 7) == 0) bid = (bid & 7) * (nwg >> 3) + (bid >> 3);  // T1
  const int bm = (bid / nbx) * GBM;
  const int bn = (bid % nbx) * GBN;

  const int wid = tid >> 6, lane = tid & 63;
  const int wr = wid >> 2, wc = wid & 3;  // 2x4 wave grid
  const int lrow = lane & 15;
  const int lkq = lane >> 4;  // k-chunk quarter 0..3

  const int NT = K / GBK;

  // stage one K-tile (A and B, 8 x 16B chunks/thread) into buffer b.
  // LDS dest linear (chunk c at byte c*16); global source inverse-swizzled:
  // chunk slot s of row r holds global k-chunk (s ^ (r&7))   [rule 21]
  auto STAGE = [&](int b, int kt) {
#pragma unroll
    for (int r = 0; r < 4; ++r) {
      const int c = r * 512 + tid;
      const int row = c >> 3;
      const int ch = (c & 7) ^ (row & 7);
      gload_lds16(A + (size_t)(bm + row) * K + kt + ch * 8,
                  (char*)&lds[b][0][0] + c * 16);
    }
#pragma unroll
    for (int r = 0; r < 4; ++r) {
      const int c = r * 512 + tid;
      const int row = c >> 3;
      const int ch = (c & 7) ^ (row & 7);
      gload_lds16(Bt + (size_t)(bn + row) * K + kt + ch * 8,
                  (char*)&lds[b][1][0] + c * 16);
    }
  };

  f32x4 acc[8][4] = {};

  // prologue: stage tiles 0 and 1
  STAGE(0, 0);
  if (NT > 1) { STAGE(1, GBK); wait_vm8(); } else { wait_vm0(); }
  bar();

  int cur = 0;
  for (int t = 0; t < NT; ++t) {
    const char* Ab = (const char*)&lds[cur][0][0];
    const char* Bb = (const char*)&lds[cur][1][0];
    short8 bfr[4], afr[4];
#pragma unroll
    for (int kk = 0; kk < 2; ++kk) {
#pragma unroll
      for (int mh = 0; mh < 2; ++mh) {
        if (mh == 0) {
#pragma unroll
          for (int j = 0; j < 4; ++j) {
            const int row = wc * 64 + j * 16 + lrow;
            const int q = (kk * 4 + lkq) ^ (row & 7);
            bfr[j] = *(const short8*)(Bb + row * 128 + q * 16);
          }
        }
#pragma unroll
        for (int i = 0; i < 4; ++i) {
          const int row = wr * 128 + (mh * 4 + i) * 16 + lrow;
          const int q = (kk * 4 + lkq) ^ (row & 7);
          afr[i] = *(const short8*)(Ab + row * 128 + q * 16);
        }
        bar();  // phase lockstep (compiler inserts lgkmcnt before MFMA use)
        __builtin_amdgcn_s_setprio(1);
#pragma unroll
        for (int i = 0; i < 4; ++i)
#pragma unroll
          for (int j = 0; j < 4; ++j)
            acc[mh * 4 + i][j] = __builtin_amdgcn_mfma_f32_16x16x32_bf16(
                afr[i], bfr[j], acc[mh * 4 + i][j], 0, 0, 0);
        __builtin_amdgcn_s_setprio(0);
        bar();  // all waves done reading this phase
      }
    }
    if (t == NT - 1) break;
    // all waves have finished reading buf[cur] (post-MFMA barrier above).
    if (t + 2 < NT) {
      STAGE(cur, (t + 2) * GBK);  // overwrite just-drained buffer
      wait_vm8();                 // tile t+1 (older 8 loads) has landed
    } else {
      wait_vm0();                 // tail: drain tile t+1
    }
    bar();  // every wave confirmed its own loads -> tile t+1 fully in LDS
    cur ^= 1;
  }

  // epilogue: C = acc + bias. C/D map: col=lane&15, row=(lane>>4)*4+reg
  const int crow0 = bm + wr * 128 + (lane >> 4) * 4;
  const int ccol0 = bn + wc * 64 + (lane & 15);
#pragma unroll
  for (int j = 0; j < 4; ++j) {
    const float bv = bias[ccol0 + j * 16];
#pragma unroll
    for (int i = 0; i < 8; ++i) {
#pragma unroll
      for (int r = 0; r < 4; ++r) {
        C[(size_t)(crow0 + i * 16 + r) * N + ccol0 + j * 16] =
            acc[i][j][r] + bv;
      }
    }
  }
}

// ---------------------------------------------------------------------------
// 128x128x64 GEMM (R1 fallback for non-256-divisible shapes).
// ---------------------------------------------------------------------------
#define BM 128
#define BN 128
#define BK 64

template <bool A_BF16>
__global__ __launch_bounds__(256) void gemm_bias_kernel(
    const void* __restrict__ Av, const short* __restrict__ Bt,
    const float* __restrict__ bias, float* __restrict__ C,
    int M, int N, int K) {
  __shared__ __align__(16) short As[BM * BK];
  __shared__ __align__(16) short Bs[BN * BK];
  const int tid = threadIdx.x;
  const int bm = blockIdx.y * BM;
  const int bn = blockIdx.x * BN;
  const int wid = tid >> 6, lane = tid & 63;
  const int wr = wid >> 1, wc = wid & 1;
  const int lrow = lane & 15;
  const int lk = (lane >> 4) * 8;

  f32x4 acc[4][4] = {};

  for (int kt = 0; kt < K; kt += BK) {
    if constexpr (A_BF16) {
      const short* A = (const short*)Av;
#pragma unroll
      for (int r = 0; r < 4; ++r) {
        const int c = r * 256 + tid;
        const int row = c >> 3, ch = c & 7;
        gload_lds16(A + (size_t)(bm + row) * K + kt + ch * 8,
                    (char*)As + c * 16);
      }
    } else {
      const float* A = (const float*)Av;
#pragma unroll
      for (int r = 0; r < 4; ++r) {
        const int c = r * 256 + tid;
        const int row = c >> 3, ch = c & 7;
        const float* src = A + (size_t)(bm + row) * K + kt + ch * 8;
        float4 f0 = *(const float4*)src;
        float4 f1 = *(const float4*)(src + 4);
        short8 v;
        v[0] = f2bf(f0.x); v[1] = f2bf(f0.y); v[2] = f2bf(f0.z); v[3] = f2bf(f0.w);
        v[4] = f2bf(f1.x); v[5] = f2bf(f1.y); v[6] = f2bf(f1.z); v[7] = f2bf(f1.w);
        *(short8*)((char*)As + c * 16) = v;
      }
    }
#pragma unroll
    for (int r = 0; r < 4; ++r) {
      const int c = r * 256 + tid;
      const int row = c >> 3, ch = c & 7;
      gload_lds16(Bt + (size_t)(bn + row) * K + kt + ch * 8,
                  (char*)Bs + c * 16);
    }
    __syncthreads();
#pragma unroll
    for (int kk = 0; kk < 2; ++kk) {
      short8 af[4], bf[4];
#pragma unroll
      for (int i = 0; i < 4; ++i)
        af[i] = *(const short8*)&As[(wr * 64 + i * 16 + lrow) * BK + kk * 32 + lk];
#pragma unroll
      for (int j = 0; j < 4; ++j)
        bf[j] = *(const short8*)&Bs[(wc * 64 + j * 16 + lrow) * BK + kk * 32 + lk];
#pragma unroll
      for (int i = 0; i < 4; ++i)
#pragma unroll
        for (int j = 0; j < 4; ++j)
          acc[i][j] = __builtin_amdgcn_mfma_f32_16x16x32_bf16(
              af[i], bf[j], acc[i][j], 0, 0, 0);
    }
    __syncthreads();
  }

  const int crow0 = bm + wr * 64 + (lane >> 4) * 4;
  const int ccol0 = bn + wc * 64 + (lane & 15);
#pragma unroll
  for (int j = 0; j < 4; ++j) {
    const float bv = bias[ccol0 + j * 16];
#pragma unroll
    for (int i = 0; i < 4; ++i) {
#pragma unroll
      for (int r = 0; r < 4; ++r) {
        C[(size_t)(crow0 + i * 16 + r) * N + ccol0 + j * 16] = acc[i][j][r] + bv;
      }
    }
  }
}

// ---------------------------------------------------------------------------
// Last-resort fallback: naive fused dequant GEMM.
// ---------------------------------------------------------------------------
__global__ __launch_bounds__(256) void naive_kernel(
    const float* __restrict__ x, const float* __restrict__ scales,
    const float* __restrict__ bias, const int* __restrict__ qw,
    const int* __restrict__ qz, float* __restrict__ out,
    int M, int K, int N) {
  long idx = (long)blockIdx.x * blockDim.x + threadIdx.x;
  if (idx >= (long)M * N) return;
  const int n = (int)(idx % N);
  const int m = (int)(idx / N);
  float acc = 0.f;
  for (int g = 0; g < K / 128; ++g) {
    const float sc = scales[(size_t)g * N + n];
    const float zp =
        (float)(((qz[(size_t)g * (N >> 3) + (n >> 3)] >> ((n & 7) * 4)) & 15) + 1);
    const float zs = zp * sc;
    for (int kw = 0; kw < 16; ++kw) {
      const int w = qw[(size_t)(g * 16 + kw) * N + n];
      const float* xp = &x[(size_t)m * K + g * 128 + kw * 8];
#pragma unroll
      for (int e = 0; e < 8; ++e)
        acc += xp[e] * ((float)((w >> (4 * e)) & 15) * sc - zs);
    }
  }
  out[idx] = acc + bias[n];
}

// ---------------------------------------------------------------------------
extern "C" void kernel_launch(void* const* d_in, const int* in_sizes, int n_in,
                              void* d_out, int out_size, void* d_ws,
                              size_t ws_size, hipStream_t stream) {
  const float* x = (const float*)d_in[0];
  const float* scales = (const float*)d_in[1];
  const float* bias = (const float*)d_in[2];
  const int* qweight = (const int*)d_in[3];
  const int* qzeros = (const int*)d_in[4];
  float* out = (float*)d_out;

  const int out_f = in_sizes[2];            // 12288
  const int kwords = in_sizes[3] / out_f;   // 512
  const int in_f = kwords * 8;              // 4096
  const int tokens = in_sizes[0] / in_f;    // 8192
  const int M = tokens, K = in_f, N = out_f;

  const size_t wt_bytes = (size_t)K * N * sizeof(short);
  const size_t xb_bytes = (size_t)M * K * sizeof(short);

  const bool div128 = (M % BM == 0) && (N % BN == 0) && (K % BK == 0) &&
                      (K % 128 == 0) && (N % 64 == 0);
  const bool div256 = (M % GBM == 0) && (N % GBN == 0) && (K % GBK == 0) &&
                      (K % 128 == 0) && (N % 64 == 0);

  if (div128 && ws_size >= wt_bytes + xb_bytes) {
    short* Wt = (short*)d_ws;
    short* xb = (short*)((char*)d_ws + wt_bytes);
    dequant_kernel<<<dim3(N / 64, K / 64), 256, 0, stream>>>(
        qweight, qzeros, scales, Wt, K, N);
    const long n8 = (long)M * K / 8;
    cvt_kernel<<<(int)((n8 + 255) / 256), 256, 0, stream>>>(x, xb, n8);
    if (div256) {
      gemm256_kernel<<<(M / GBM) * (N / GBN), 512, 0, stream>>>(
          xb, Wt, bias, out, M, N, K);
    } else {
      gemm_bias_kernel<true><<<dim3(N / BN, M / BM), 256, 0, stream>>>(
          xb, Wt, bias, out, M, N, K);
    }
  } else if (div128 && ws_size >= wt_bytes) {
    short* Wt = (short*)d_ws;
    dequant_kernel<<<dim3(N / 64, K / 64), 256, 0, stream>>>(
        qweight, qzeros, scales, Wt, K, N);
    gemm_bias_kernel<false><<<dim3(N / BN, M / BM), 256, 0, stream>>>(
        x, Wt, bias, out, M, N, K);
  } else {
    const long total = (long)M * N;
    naive_kernel<<<(int)((total + 255) / 256), 256, 0, stream>>>(
        x, scales, bias, qweight, qzeros, out, M, K, N);
  }
}